// Round 6
// baseline (164.749 us; speedup 1.0000x reference)
//
#include <hip/hip_runtime.h>

#define BN 8192
#define BD 256
#define NTRIALS 150

// EXACT R1/R4 reduce — proven bitwise-compatible with the reference twice.
__device__ __forceinline__ float wave_reduce_sum(float v) {
    #pragma unroll
    for (int m = 32; m > 0; m >>= 1) v += __shfl_xor(v, m, 64);
    return v;
}

// Kernel 1: count genuine (tgt == 0). Single block. (verbatim from passing R1/R4)
__global__ __launch_bounds__(1024) void count_genuine_kernel(
    const int* __restrict__ tgt, int* __restrict__ cnt)
{
    __shared__ int lds[16];
    const int t = threadIdx.x;
    int c = 0;
    for (int i = t; i < BN; i += 1024) c += (tgt[i] == 0) ? 1 : 0;
    #pragma unroll
    for (int m = 32; m > 0; m >>= 1) c += __shfl_xor(c, m, 64);
    if ((t & 63) == 0) lds[t >> 6] = c;
    __syncthreads();
    if (t == 0) {
        int s = 0;
        #pragma unroll
        for (int w = 0; w < 16; ++w) s += lds[w];
        *cnt = s;
    }
}

// Kernel 2: sq[i] = sum_d hd[i][d]^2. One wave per row. (verbatim from passing R1/R4)
__global__ __launch_bounds__(256) void sqnorm_kernel(
    const float* __restrict__ hd, float* __restrict__ sq)
{
    const int lane = threadIdx.x & 63;
    const int row  = blockIdx.x * 4 + (threadIdx.x >> 6);
    const float4 a = *reinterpret_cast<const float4*>(hd + row * BD + lane * 4);
    float s = a.x * a.x + a.y * a.y + a.z * a.z + a.w * a.w;
    s = wave_reduce_sum(s);
    if (lane == 0) sq[row] = s;
}

// One trial for anchor S: process slot (c,bj,sqc); prefetch trial PFT into the
// same slot. Arithmetic sequence is the exact R1/R4 AST. The hit action sets a
// wave-uniform flag instead of goto; else-if preserves no-update-on-hit.
#define TRIAL_STEP(S, CSLOT, BJSLOT, SQSLOT, PFT)                               \
    if (act##S) {                                                               \
        const int    c_  = CSLOT;                                               \
        const float4 bj  = BJSLOT;                                              \
        const float  sqc = SQSLOT;                                              \
        if ((PFT) < NTRIALS) {                                                  \
            int c2 = (int)(unrow##S[PFT] * lnf##S);                             \
            c2 = min(c2, lnm1##S);                                              \
            CSLOT  = c2;                                                        \
            BJSLOT = *reinterpret_cast<const float4*>(hd + c2 * BD + lane * 4); \
            SQSLOT = sq[c2];                                                    \
        }                                                                       \
        float p = a##S.x * bj.x + a##S.y * bj.y + a##S.z * bj.z + a##S.w * bj.w;\
        const float dn = (sqi##S - 2.0f * wave_reduce_sum(p)) + sqc;            \
        const float z = dst_pos##S - dn;                                        \
        if ((z < 0.0f) && (z + margin > 0.0f)) { chosen##S = c_; act##S = false; } \
        else if (dn < best##S) { best##S = dn; best_c##S = c_; }                \
    }

// Prologue helper: load trial T of anchor S into a slot.
#define PREFETCH_SLOT(S, CSLOT, BJSLOT, SQSLOT, T)                              \
    {                                                                           \
        int c = (int)(unrow##S[T] * lnf##S);                                    \
        c = min(c, lnm1##S);                                                    \
        CSLOT  = c;                                                             \
        BJSLOT = *reinterpret_cast<const float4*>(hd + c * BD + lane * 4);      \
        SQSLOT = sq[c];                                                         \
    }

// Per-anchor setup: anchor row, lens, positive index/distance (exact R4 text),
// and the anchor+positive output rows.
#define ANCHOR_SETUP(S, IDX)                                                    \
    const int i##S = (IDX);                                                     \
    const float4 a##S = *reinterpret_cast<const float4*>(hd + i##S * BD + lane * 4); \
    const float sqi##S = sq[i##S];                                              \
    const int ti##S = tgt[i##S];                                                \
    const int len_pos##S = (ti##S == 0) ? ng : (BN - ng);                       \
    const int len_neg##S = (ti##S == 0) ? (BN - ng) : ng;                       \
    const bool excl##S = (i##S < len_pos##S);                                   \
    const int  eff##S  = len_pos##S - (excl##S ? 1 : 0);                        \
    const float up##S  = u_pos[i##S];                                           \
    int u##S = (int)(up##S * (float)eff##S);                                    \
    u##S = min(u##S, eff##S - 1);                                               \
    const int pos_idx##S = u##S + ((excl##S && (u##S >= i##S)) ? 1 : 0);        \
    const float4 bp##S = *reinterpret_cast<const float4*>(hd + pos_idx##S * BD + lane * 4); \
    float pp##S = a##S.x * bp##S.x + a##S.y * bp##S.y + a##S.z * bp##S.z + a##S.w * bp##S.w; \
    const float dot_pos##S = wave_reduce_sum(pp##S);                            \
    const float dst_pos##S = (sqi##S - 2.0f * dot_pos##S) + sq[pos_idx##S];     \
    float* orow##S = out + i##S * (3 * BD);                                     \
    *reinterpret_cast<float4*>(orow##S + lane * 4) = a##S;                      \
    *reinterpret_cast<float4*>(orow##S + BD + lane * 4) = bp##S;                \
    const float lnf##S  = (float)len_neg##S;                                    \
    const int   lnm1##S = len_neg##S - 1;                                       \
    const float* unrow##S = u_neg + i##S * NTRIALS;                             \
    int   chosen##S = -1;                                                       \
    float best##S   = __builtin_inff();                                         \
    int   best_c##S = 0;                                                        \
    bool  act##S    = true;

// Kernel 3: TWO anchors per wave, trials sequential per anchor, two independent
// dependency chains interleaved; depth-2 prefetch per anchor (as passing R4).
__global__ __launch_bounds__(256) void triplet_kernel(
    const float* __restrict__ hd, const int* __restrict__ tgt,
    const float* __restrict__ margin_p, const float* __restrict__ u_pos,
    const float* __restrict__ u_neg, const float* __restrict__ sq,
    const int* __restrict__ cnt, float* __restrict__ out)
{
    const int lane = threadIdx.x & 63;
    const int gw   = blockIdx.x * 4 + (threadIdx.x >> 6);

    const int ng = *cnt;
    const float margin = margin_p[0];

    ANCHOR_SETUP(A, 2 * gw)
    ANCHOR_SETUP(B, 2 * gw + 1)

    // prologue: per anchor, slots 0/1 hold trials 0/1
    int cA0, cA1, cB0, cB1;
    float4 bjA0, bjA1, bjB0, bjB1;
    float sqA0, sqA1, sqB0, sqB1;
    PREFETCH_SLOT(A, cA0, bjA0, sqA0, 0)
    PREFETCH_SLOT(B, cB0, bjB0, sqB0, 0)
    PREFETCH_SLOT(A, cA1, bjA1, sqA1, 1)
    PREFETCH_SLOT(B, cB1, bjB1, sqB1, 1)

    for (int t = 0; t < NTRIALS; t += 2) {
        TRIAL_STEP(A, cA0, bjA0, sqA0, t + 2)   // anchor A, trial t
        TRIAL_STEP(B, cB0, bjB0, sqB0, t + 2)   // anchor B, trial t
        TRIAL_STEP(A, cA1, bjA1, sqA1, t + 3)   // anchor A, trial t+1
        TRIAL_STEP(B, cB1, bjB1, sqB1, t + 3)   // anchor B, trial t+1
        if (!actA && !actB) break;
    }

    const int negA = (chosenA >= 0) ? chosenA : best_cA;
    const int negB = (chosenB >= 0) ? chosenB : best_cB;

    const float4 bnA = *reinterpret_cast<const float4*>(hd + negA * BD + lane * 4);
    *reinterpret_cast<float4*>(orowA + 2 * BD + lane * 4) = bnA;
    const float4 bnB = *reinterpret_cast<const float4*>(hd + negB * BD + lane * 4);
    *reinterpret_cast<float4*>(orowB + 2 * BD + lane * 4) = bnB;
}

extern "C" void kernel_launch(void* const* d_in, const int* in_sizes, int n_in,
                              void* d_out, int out_size, void* d_ws, size_t ws_size,
                              hipStream_t stream) {
    const float* hd     = (const float*)d_in[0];
    const int*   tgt    = (const int*)d_in[1];
    const float* margin = (const float*)d_in[2];
    const float* u_pos  = (const float*)d_in[3];
    const float* u_neg  = (const float*)d_in[4];
    float* out = (float*)d_out;

    float* sq  = (float*)d_ws;
    int*   cnt = (int*)((char*)d_ws + BN * sizeof(float));

    count_genuine_kernel<<<1, 1024, 0, stream>>>(tgt, cnt);
    sqnorm_kernel<<<BN / 4, 256, 0, stream>>>(hd, sq);
    triplet_kernel<<<BN / 8, 256, 0, stream>>>(hd, tgt, margin, u_pos, u_neg, sq, cnt, out);
}

// Round 7
// 105.604 us; speedup vs baseline: 1.5601x; 1.5601x over previous
//
#include <hip/hip_runtime.h>

#define BN 8192
#define BD 256
#define NTRIALS 150

// EXACT R1/R4 reduce — proven bitwise-compatible with the reference three times.
__device__ __forceinline__ float wave_reduce_sum(float v) {
    #pragma unroll
    for (int m = 32; m > 0; m >>= 1) v += __shfl_xor(v, m, 64);
    return v;
}

// Kernel 1: count genuine (tgt == 0). Single block. (verbatim from passing R1/R4)
__global__ __launch_bounds__(1024) void count_genuine_kernel(
    const int* __restrict__ tgt, int* __restrict__ cnt)
{
    __shared__ int lds[16];
    const int t = threadIdx.x;
    int c = 0;
    for (int i = t; i < BN; i += 1024) c += (tgt[i] == 0) ? 1 : 0;
    #pragma unroll
    for (int m = 32; m > 0; m >>= 1) c += __shfl_xor(c, m, 64);
    if ((t & 63) == 0) lds[t >> 6] = c;
    __syncthreads();
    if (t == 0) {
        int s = 0;
        #pragma unroll
        for (int w = 0; w < 16; ++w) s += lds[w];
        *cnt = s;
    }
}

// Kernel 2: sq[i] = sum_d hd[i][d]^2. One wave per row. (verbatim from passing R1/R4)
__global__ __launch_bounds__(256) void sqnorm_kernel(
    const float* __restrict__ hd, float* __restrict__ sq)
{
    const int lane = threadIdx.x & 63;
    const int row  = blockIdx.x * 4 + (threadIdx.x >> 6);
    const float4 a = *reinterpret_cast<const float4*>(hd + row * BD + lane * 4);
    float s = a.x * a.x + a.y * a.y + a.z * a.z + a.w * a.w;
    s = wave_reduce_sum(s);
    if (lane == 0) sq[row] = s;
}

// Compute one trial's dn (exact R4 TRIAL_STEP text, minus the trailing
// compare/update which moves verbatim into TRIAL_CHECK). Prefetches trial PFT
// into the same slot. No control flow -> the scheduler can overlap the three
// slots' shuffle chains within a group.
#define TRIAL_COMPUTE(CSLOT, BJSLOT, SQSLOT, PFT, CSAVE, DNSAVE)                \
    {                                                                           \
        const int    c_  = CSLOT;                                               \
        const float4 bj  = BJSLOT;                                              \
        const float  sqc = SQSLOT;                                              \
        if ((PFT) < NTRIALS) {                                                  \
            int c2 = (int)(unrow[PFT] * lnf);                                   \
            c2 = min(c2, lnm1);                                                 \
            CSLOT  = c2;                                                        \
            BJSLOT = *reinterpret_cast<const float4*>(hd + c2 * BD + lane * 4); \
            SQSLOT = sq[c2];                                                    \
        }                                                                       \
        float p = a.x * bj.x + a.y * bj.y + a.z * bj.z + a.w * bj.w;            \
        const float dn = (sqi - 2.0f * wave_reduce_sum(p)) + sqc;               \
        CSAVE  = c_;                                                            \
        DNSAVE = dn;                                                            \
    }

// In-order break / strict-< argmin semantics, identical text to R4's trailer.
// z is a plain subtract (exact op) so deferring it cannot change bits.
#define TRIAL_CHECK(CSAVE, DNSAVE)                                              \
    {                                                                           \
        const float z = dst_pos - (DNSAVE);                                     \
        if ((z < 0.0f) && (z + margin > 0.0f)) { chosen = (CSAVE); goto done; } \
        if ((DNSAVE) < best) { best = (DNSAVE); best_c = (CSAVE); }             \
    }

// Kernel 3: one wave per anchor; trials scanned in groups of 3 with branchless
// grouped compute (3 overlapped shuffle chains) + in-order grouped checks.
__global__ __launch_bounds__(256) void triplet_kernel(
    const float* __restrict__ hd, const int* __restrict__ tgt,
    const float* __restrict__ margin_p, const float* __restrict__ u_pos,
    const float* __restrict__ u_neg, const float* __restrict__ sq,
    const int* __restrict__ cnt, float* __restrict__ out)
{
    const int lane = threadIdx.x & 63;
    const int i    = blockIdx.x * 4 + (threadIdx.x >> 6);

    // anchor row in registers (float4 per lane: 64*4 = 256 = D)
    const float4 a = *reinterpret_cast<const float4*>(hd + i * BD + lane * 4);
    const float sqi = sq[i];

    const int ng = *cnt;
    const int ti = tgt[i];
    const int len_pos = (ti == 0) ? ng : (BN - ng);
    const int len_neg = (ti == 0) ? (BN - ng) : ng;

    // positive index — exact integer/fp32 replication of the reference
    const bool excl = (i < len_pos);
    const int  eff  = len_pos - (excl ? 1 : 0);
    const float up  = u_pos[i];
    int u = (int)(up * (float)eff);        // fp32 multiply, trunc toward zero
    u = min(u, eff - 1);
    const int pos_idx = u + ((excl && (u >= i)) ? 1 : 0);

    // dst_pos = (sq_i - 2*dot) + sq_j  (same expression/order as R1/R4)
    const float4 bp = *reinterpret_cast<const float4*>(hd + pos_idx * BD + lane * 4);
    float pp = a.x * bp.x + a.y * bp.y + a.z * bp.z + a.w * bp.w;
    const float dot_pos = wave_reduce_sum(pp);
    const float dst_pos = (sqi - 2.0f * dot_pos) + sq[pos_idx];

    // write anchor + positive rows now (overlaps with the scan)
    float* orow = out + i * (3 * BD);
    *reinterpret_cast<float4*>(orow + lane * 4) = a;
    *reinterpret_cast<float4*>(orow + BD + lane * 4) = bp;

    const float margin = margin_p[0];
    const float lnf    = (float)len_neg;
    const int   lnm1   = len_neg - 1;

    int   chosen = -1;
    float best   = __builtin_inff();
    int   best_c = 0;
    const float* unrow = u_neg + i * NTRIALS;

    // prologue: prefetch trials 0,1,2 into slots A,B,C
    int cA, cB, cC; float4 bjA, bjB, bjC; float sqA, sqB, sqC;
    {
        int c = (int)(unrow[0] * lnf);
        c = min(c, lnm1);
        cA = c;
        bjA = *reinterpret_cast<const float4*>(hd + c * BD + lane * 4);
        sqA = sq[c];
    }
    {
        int c = (int)(unrow[1] * lnf);
        c = min(c, lnm1);
        cB = c;
        bjB = *reinterpret_cast<const float4*>(hd + c * BD + lane * 4);
        sqB = sq[c];
    }
    {
        int c = (int)(unrow[2] * lnf);
        c = min(c, lnm1);
        cC = c;
        bjC = *reinterpret_cast<const float4*>(hd + c * BD + lane * 4);
        sqC = sq[c];
    }

    for (int t = 0; t < NTRIALS; t += 3) {
        int cs0, cs1, cs2;
        float dn0, dn1, dn2;
        TRIAL_COMPUTE(cA, bjA, sqA, t + 3, cs0, dn0)   // trial t
        TRIAL_COMPUTE(cB, bjB, sqB, t + 4, cs1, dn1)   // trial t+1
        TRIAL_COMPUTE(cC, bjC, sqC, t + 5, cs2, dn2)   // trial t+2
        TRIAL_CHECK(cs0, dn0)
        TRIAL_CHECK(cs1, dn1)
        TRIAL_CHECK(cs2, dn2)
    }
done:
    ;
    const int neg = (chosen >= 0) ? chosen : best_c;

    const float4 bn = *reinterpret_cast<const float4*>(hd + neg * BD + lane * 4);
    *reinterpret_cast<float4*>(orow + 2 * BD + lane * 4) = bn;
}

extern "C" void kernel_launch(void* const* d_in, const int* in_sizes, int n_in,
                              void* d_out, int out_size, void* d_ws, size_t ws_size,
                              hipStream_t stream) {
    const float* hd     = (const float*)d_in[0];
    const int*   tgt    = (const int*)d_in[1];
    const float* margin = (const float*)d_in[2];
    const float* u_pos  = (const float*)d_in[3];
    const float* u_neg  = (const float*)d_in[4];
    float* out = (float*)d_out;

    float* sq  = (float*)d_ws;
    int*   cnt = (int*)((char*)d_ws + BN * sizeof(float));

    count_genuine_kernel<<<1, 1024, 0, stream>>>(tgt, cnt);
    sqnorm_kernel<<<BN / 4, 256, 0, stream>>>(hd, sq);
    triplet_kernel<<<BN / 4, 256, 0, stream>>>(hd, tgt, margin, u_pos, u_neg, sq, cnt, out);
}

// Round 8
// 90.956 us; speedup vs baseline: 1.8113x; 1.1610x over previous
//
#include <hip/hip_runtime.h>

#define BN 8192
#define BD 256
#define NTRIALS 150

// EXACT R1/R4/R7 reduce — proven bitwise-compatible with the reference four times.
__device__ __forceinline__ float wave_reduce_sum(float v) {
    #pragma unroll
    for (int m = 32; m > 0; m >>= 1) v += __shfl_xor(v, m, 64);
    return v;
}

// Kernel 1: count genuine (tgt == 0). Single block. (verbatim from passing R1/R4/R7)
__global__ __launch_bounds__(1024) void count_genuine_kernel(
    const int* __restrict__ tgt, int* __restrict__ cnt)
{
    __shared__ int lds[16];
    const int t = threadIdx.x;
    int c = 0;
    for (int i = t; i < BN; i += 1024) c += (tgt[i] == 0) ? 1 : 0;
    #pragma unroll
    for (int m = 32; m > 0; m >>= 1) c += __shfl_xor(c, m, 64);
    if ((t & 63) == 0) lds[t >> 6] = c;
    __syncthreads();
    if (t == 0) {
        int s = 0;
        #pragma unroll
        for (int w = 0; w < 16; ++w) s += lds[w];
        *cnt = s;
    }
}

// Kernel 2: sq[i] = sum_d hd[i][d]^2. One wave per row. (verbatim from passing R1/R4/R7)
__global__ __launch_bounds__(256) void sqnorm_kernel(
    const float* __restrict__ hd, float* __restrict__ sq)
{
    const int lane = threadIdx.x & 63;
    const int row  = blockIdx.x * 4 + (threadIdx.x >> 6);
    const float4 a = *reinterpret_cast<const float4*>(hd + row * BD + lane * 4);
    float s = a.x * a.x + a.y * a.y + a.z * a.z + a.w * a.w;
    s = wave_reduce_sum(s);
    if (lane == 0) sq[row] = s;
}

// Compute one trial's dn — exact R7 compute text with the prefetch made
// UNCONDITIONAL (caller guarantees PFT < NTRIALS). No branches -> the three
// slots' shuffle chains share one basic block and can be pipelined.
#define TRIAL_COMPUTE_PF(CSLOT, BJSLOT, SQSLOT, PFT, CSAVE, DNSAVE)             \
    {                                                                           \
        const int    c_  = CSLOT;                                               \
        const float4 bj  = BJSLOT;                                              \
        const float  sqc = SQSLOT;                                              \
        {                                                                       \
            int c2 = (int)(unrow[PFT] * lnf);                                   \
            c2 = min(c2, lnm1);                                                 \
            CSLOT  = c2;                                                        \
            BJSLOT = *reinterpret_cast<const float4*>(hd + c2 * BD + lane * 4); \
            SQSLOT = sq[c2];                                                    \
        }                                                                       \
        float p = a.x * bj.x + a.y * bj.y + a.z * bj.z + a.w * bj.w;            \
        const float dn = (sqi - 2.0f * wave_reduce_sum(p)) + sqc;               \
        CSAVE  = c_;                                                            \
        DNSAVE = dn;                                                            \
    }

// Same compute text, no prefetch (final peeled group).
#define TRIAL_COMPUTE_NP(CSLOT, BJSLOT, SQSLOT, CSAVE, DNSAVE)                  \
    {                                                                           \
        const int    c_  = CSLOT;                                               \
        const float4 bj  = BJSLOT;                                              \
        const float  sqc = SQSLOT;                                              \
        float p = a.x * bj.x + a.y * bj.y + a.z * bj.z + a.w * bj.w;            \
        const float dn = (sqi - 2.0f * wave_reduce_sum(p)) + sqc;               \
        CSAVE  = c_;                                                            \
        DNSAVE = dn;                                                            \
    }

// In-order break / strict-< argmin semantics, identical text to R4/R7's trailer.
#define TRIAL_CHECK(CSAVE, DNSAVE)                                              \
    {                                                                           \
        const float z = dst_pos - (DNSAVE);                                     \
        if ((z < 0.0f) && (z + margin > 0.0f)) { chosen = (CSAVE); goto done; } \
        if ((DNSAVE) < best) { best = (DNSAVE); best_c = (CSAVE); }             \
    }

// Kernel 3: one wave per anchor; trials in groups of 3, branch-free grouped
// compute (3 overlapped shuffle chains in one BB) + in-order grouped checks.
__global__ __launch_bounds__(256) void triplet_kernel(
    const float* __restrict__ hd, const int* __restrict__ tgt,
    const float* __restrict__ margin_p, const float* __restrict__ u_pos,
    const float* __restrict__ u_neg, const float* __restrict__ sq,
    const int* __restrict__ cnt, float* __restrict__ out)
{
    const int lane = threadIdx.x & 63;
    const int i    = blockIdx.x * 4 + (threadIdx.x >> 6);

    // anchor row in registers (float4 per lane: 64*4 = 256 = D)
    const float4 a = *reinterpret_cast<const float4*>(hd + i * BD + lane * 4);
    const float sqi = sq[i];

    const int ng = *cnt;
    const int ti = tgt[i];
    const int len_pos = (ti == 0) ? ng : (BN - ng);
    const int len_neg = (ti == 0) ? (BN - ng) : ng;

    // positive index — exact integer/fp32 replication of the reference
    const bool excl = (i < len_pos);
    const int  eff  = len_pos - (excl ? 1 : 0);
    const float up  = u_pos[i];
    int u = (int)(up * (float)eff);        // fp32 multiply, trunc toward zero
    u = min(u, eff - 1);
    const int pos_idx = u + ((excl && (u >= i)) ? 1 : 0);

    // dst_pos = (sq_i - 2*dot) + sq_j  (same expression/order as R1/R4/R7)
    const float4 bp = *reinterpret_cast<const float4*>(hd + pos_idx * BD + lane * 4);
    float pp = a.x * bp.x + a.y * bp.y + a.z * bp.z + a.w * bp.w;
    const float dot_pos = wave_reduce_sum(pp);
    const float dst_pos = (sqi - 2.0f * dot_pos) + sq[pos_idx];

    // write anchor + positive rows now (overlaps with the scan)
    float* orow = out + i * (3 * BD);
    *reinterpret_cast<float4*>(orow + lane * 4) = a;
    *reinterpret_cast<float4*>(orow + BD + lane * 4) = bp;

    const float margin = margin_p[0];
    const float lnf    = (float)len_neg;
    const int   lnm1   = len_neg - 1;

    int   chosen = -1;
    float best   = __builtin_inff();
    int   best_c = 0;
    const float* unrow = u_neg + i * NTRIALS;

    // prologue: prefetch trials 0,1,2 into slots A,B,C
    int cA, cB, cC; float4 bjA, bjB, bjC; float sqA, sqB, sqC;
    {
        int c = (int)(unrow[0] * lnf);
        c = min(c, lnm1);
        cA = c;
        bjA = *reinterpret_cast<const float4*>(hd + c * BD + lane * 4);
        sqA = sq[c];
    }
    {
        int c = (int)(unrow[1] * lnf);
        c = min(c, lnm1);
        cB = c;
        bjB = *reinterpret_cast<const float4*>(hd + c * BD + lane * 4);
        sqB = sq[c];
    }
    {
        int c = (int)(unrow[2] * lnf);
        c = min(c, lnm1);
        cC = c;
        bjC = *reinterpret_cast<const float4*>(hd + c * BD + lane * 4);
        sqC = sq[c];
    }

    // main loop: t = 0,3,...,144 — computes trials t..t+2, prefetches t+3..t+5
    // (always in range, so prefetch is unconditional: no branches in the group)
    for (int t = 0; t < NTRIALS - 3; t += 3) {
        int cs0, cs1, cs2;
        float dn0, dn1, dn2;
        TRIAL_COMPUTE_PF(cA, bjA, sqA, t + 3, cs0, dn0)   // trial t
        TRIAL_COMPUTE_PF(cB, bjB, sqB, t + 4, cs1, dn1)   // trial t+1
        TRIAL_COMPUTE_PF(cC, bjC, sqC, t + 5, cs2, dn2)   // trial t+2
        TRIAL_CHECK(cs0, dn0)
        TRIAL_CHECK(cs1, dn1)
        TRIAL_CHECK(cs2, dn2)
    }
    // peeled final group: trials 147,148,149 — no prefetch
    {
        int cs0, cs1, cs2;
        float dn0, dn1, dn2;
        TRIAL_COMPUTE_NP(cA, bjA, sqA, cs0, dn0)
        TRIAL_COMPUTE_NP(cB, bjB, sqB, cs1, dn1)
        TRIAL_COMPUTE_NP(cC, bjC, sqC, cs2, dn2)
        TRIAL_CHECK(cs0, dn0)
        TRIAL_CHECK(cs1, dn1)
        TRIAL_CHECK(cs2, dn2)
    }
done:
    ;
    const int neg = (chosen >= 0) ? chosen : best_c;

    const float4 bn = *reinterpret_cast<const float4*>(hd + neg * BD + lane * 4);
    *reinterpret_cast<float4*>(orow + 2 * BD + lane * 4) = bn;
}

extern "C" void kernel_launch(void* const* d_in, const int* in_sizes, int n_in,
                              void* d_out, int out_size, void* d_ws, size_t ws_size,
                              hipStream_t stream) {
    const float* hd     = (const float*)d_in[0];
    const int*   tgt    = (const int*)d_in[1];
    const float* margin = (const float*)d_in[2];
    const float* u_pos  = (const float*)d_in[3];
    const float* u_neg  = (const float*)d_in[4];
    float* out = (float*)d_out;

    float* sq  = (float*)d_ws;
    int*   cnt = (int*)((char*)d_ws + BN * sizeof(float));

    count_genuine_kernel<<<1, 1024, 0, stream>>>(tgt, cnt);
    sqnorm_kernel<<<BN / 4, 256, 0, stream>>>(hd, sq);
    triplet_kernel<<<BN / 4, 256, 0, stream>>>(hd, tgt, margin, u_pos, u_neg, sq, cnt, out);
}